// Round 8
// baseline (53.714 us; speedup 1.0000x reference)
//
#include <hip/hip_runtime.h>

// BKT: B=4096 students, T=512 timesteps, K=2048 skills.
// R8: bucket table replaces linked lists. R6 showed the win comes from
// skipping LDS pointer chases (dependent ds_read ~120cy/hop, wave pays
// max-over-lanes); R7 showed param staging is net-negative. This version
// makes the per-skill "chain" a fixed C=4 arrival-ordered bucket:
//   build:  slot = atomicAdd(count[sk]) (counts packed 2-per-int),
//           buck[sk][slot] = (ushort)t
//   query:  one ds_read (packed count) + one 8B ds_read (whole bucket),
//           invalidate entries >= t or >= n, sort4 network, apply in order.
// Walk latency collapses from ~600-2400cy dependent chain to ~1 LDS access.
// Overflow n>4 (~50 chains per grid, Poisson(0.25) tail): exact fallback =
// forward scan of staged sk_s/resp_s row (naturally time-ordered).
// LDS 23KB -> 6 blocks/CU = 24 waves/CU.

#define BKT_B 4096
#define BKT_T 512
#define BKT_K 2048
#define BLK   256
#define TPT   (BKT_T / BLK)   // 2 timesteps per thread
#define CAP   4

__device__ __forceinline__ float bkt_update(float p, float r, float ss,
                                            float gg, float tt) {
  float num, den;
  if (r > 0.5f) {            // correct response
    num = p * (1.0f - ss);
    den = num + (1.0f - p) * gg;
  } else {                   // incorrect response
    num = p * ss;
    den = num + (1.0f - p) * (1.0f - gg);
  }
  const float q = num / den; // Bayesian posterior
  return q + (1.0f - q) * tt;// learning transition
}

__global__ __launch_bounds__(BLK) void bkt_kernel(
    const int* __restrict__ skills,
    const float* __restrict__ resp,
    const float* __restrict__ k0,
    const float* __restrict__ tp,
    const float* __restrict__ gp,
    const float* __restrict__ sp,
    float* __restrict__ out) {
  __shared__ int cnt_s[BKT_K / 2];                     // 2 x u16 counts / int
  __shared__ __align__(16) unsigned short buck_s[BKT_K][CAP];
  __shared__ unsigned short sk_s[BKT_T];
  __shared__ float resp_s[BKT_T];

  const int b = blockIdx.x;
  const int base = b * BKT_T;
  const int tid = threadIdx.x;

  // coalesced loads of this student's row
  int   sk[TPT];
  float rr[TPT];
#pragma unroll
  for (int u = 0; u < TPT; ++u) {
    const int t = tid + u * BLK;
    sk[u] = skills[base + t];
    rr[u] = resp[base + t];
  }

  // zero packed counts: 4KB / 256 threads = one int4 store each
  ((int4*)cnt_s)[tid] = make_int4(0, 0, 0, 0);

  // stage row (fallback path + responses for replay)
#pragma unroll
  for (int u = 0; u < TPT; ++u) {
    const int t = tid + u * BLK;
    sk_s[t] = (unsigned short)sk[u];
    resp_s[t] = rr[u];
  }
  __syncthreads();

  // build buckets: arrival-ordered slots via packed atomicAdd
#pragma unroll
  for (int u = 0; u < TPT; ++u) {
    const int t = tid + u * BLK;
    const int s_ = sk[u];
    const int sh = (s_ & 1) * 16;
    const int old = atomicAdd(&cnt_s[s_ >> 1], 1 << sh);
    const int slot = (old >> sh) & 0xFFFF;
    if (slot < CAP) buck_s[s_][slot] = (unsigned short)t;
  }
  __syncthreads();

#pragma unroll
  for (int u = 0; u < TPT; ++u) {
    const int t = tid + u * BLK;
    const int s_ = sk[u];
    const int n = (cnt_s[s_ >> 1] >> ((s_ & 1) * 16)) & 0xFFFF;

    float p = k0[s_];                    // prior (answer when rank == 0)

    if (n > 1) {
      if (n <= CAP) {
        // whole bucket in one 8B read
        const uint2 bv = *(const uint2*)&buck_s[s_][0];
        unsigned short e[CAP];
        e[0] = (unsigned short)(bv.x & 0xFFFF);
        e[1] = (unsigned short)(bv.x >> 16);
        e[2] = (unsigned short)(bv.y & 0xFFFF);
        e[3] = (unsigned short)(bv.y >> 16);
        // invalidate: slots beyond n, and touches at/after t
#pragma unroll
        for (int i = 0; i < CAP; ++i)
          if (i >= n || e[i] >= t) e[i] = 0xFFFF;
        // sort4 ascending (invalid 0xFFFF sinks to the end)
#define CSWAP(a_, b_) { unsigned short lo = min(e[a_], e[b_]); \
                        unsigned short hi = max(e[a_], e[b_]); \
                        e[a_] = lo; e[b_] = hi; }
        CSWAP(0, 1) CSWAP(2, 3) CSWAP(0, 2) CSWAP(1, 3) CSWAP(1, 2)
#undef CSWAP
        if (e[0] != 0xFFFF) {            // rank > 0: replay in time order
          const float ss = sp[s_];
          const float gg = gp[s_];
          const float tt = tp[s_];
#pragma unroll
          for (int i = 0; i < CAP; ++i)
            if (e[i] != 0xFFFF) p = bkt_update(p, resp_s[e[i]], ss, gg, tt);
        }
      } else {
        // rare overflow (n > CAP): exact forward scan of the staged row
        const float ss = sp[s_];
        const float gg = gp[s_];
        const float tt = tp[s_];
        for (int j = 0; j < t; ++j)
          if (sk_s[j] == (unsigned short)s_)
            p = bkt_update(p, resp_s[j], ss, gg, tt);
      }
    }

    out[base + t] = p;                   // emit pre-update mastery
  }
}

extern "C" void kernel_launch(void* const* d_in, const int* in_sizes, int n_in,
                              void* d_out, int out_size, void* d_ws, size_t ws_size,
                              hipStream_t stream) {
  const int*   skills = (const int*)d_in[0];
  const float* resp   = (const float*)d_in[1];
  const float* k0     = (const float*)d_in[2];
  const float* tp     = (const float*)d_in[3];
  const float* gp     = (const float*)d_in[4];
  const float* sp     = (const float*)d_in[5];
  float* out = (float*)d_out;

  bkt_kernel<<<BKT_B, BLK, 0, stream>>>(skills, resp, k0, tp, gp, sp, out);
}

// Round 9
// 36.753 us; speedup vs baseline: 1.4615x; 1.4615x over previous
//
#include <hip/hip_runtime.h>

// BKT: B=4096 students, T=512 timesteps, K=2048 skills.
// R9 = R8's bucket design with the straggler landmine removed.
// R8 counters: dur 53.6us, avg occupancy 8.7% (2.8 waves/CU vs 24 resident)
// => tail-dominated. Culprit: overflow fallback = runtime-bounded divergent
// DEPENDENT scalar LDS loop (~120cy x up to 512 iter = ~25us per straggler
// lane; ~300 lanes grid-wide gate the kernel end). This version:
//  - per-skill C=4 arrival-ordered buckets (atomicAdd slots, packed counts),
//    query = one 8B ds_read + sort4 network, NO dependent pointer chases;
//  - overflow (n>4, ~55 (student,skill) pairs/grid): vectorized forward scan
//    of the staged skill row, 8 entries per ds_read_b128, independent loads
//    (pipelined, ~64 iter ~1.3K cy worst case instead of 60K);
//  - k0[sk] gather issued BEFORE the LDS build phase (latency hides under
//    init + atomics + barrier).
// LDS 23KB -> 6 blocks/CU = 24 waves/CU.

#define BKT_B 4096
#define BKT_T 512
#define BKT_K 2048
#define BLK   256
#define TPT   (BKT_T / BLK)   // 2 timesteps per thread
#define CAP   4

__device__ __forceinline__ float bkt_update(float p, float r, float ss,
                                            float gg, float tt) {
  float num, den;
  if (r > 0.5f) {            // correct response
    num = p * (1.0f - ss);
    den = num + (1.0f - p) * gg;
  } else {                   // incorrect response
    num = p * ss;
    den = num + (1.0f - p) * (1.0f - gg);
  }
  const float q = num / den; // Bayesian posterior
  return q + (1.0f - q) * tt;// learning transition
}

__global__ __launch_bounds__(BLK) void bkt_kernel(
    const int* __restrict__ skills,
    const float* __restrict__ resp,
    const float* __restrict__ k0,
    const float* __restrict__ tp,
    const float* __restrict__ gp,
    const float* __restrict__ sp,
    float* __restrict__ out) {
  __shared__ int cnt_s[BKT_K / 2];                      // 2 x u16 counts / int
  __shared__ __align__(16) unsigned short buck_s[BKT_K][CAP];
  __shared__ __align__(16) unsigned short sk_s[BKT_T];  // overflow-scan row
  __shared__ float resp_s[BKT_T];

  const int b = blockIdx.x;
  const int base = b * BKT_T;
  const int tid = threadIdx.x;

  // coalesced loads of this student's row; k0 gather issued immediately so
  // its latency hides under the LDS init/build phase
  int   sk[TPT];
  float rr[TPT];
  float k0v[TPT];
#pragma unroll
  for (int u = 0; u < TPT; ++u) {
    const int t = tid + u * BLK;
    sk[u] = skills[base + t];
    rr[u] = resp[base + t];
  }
#pragma unroll
  for (int u = 0; u < TPT; ++u)
    k0v[u] = k0[sk[u]];

  // zero packed counts: 4KB / 256 threads = one int4 store each
  ((int4*)cnt_s)[tid] = make_int4(0, 0, 0, 0);

  // stage row
#pragma unroll
  for (int u = 0; u < TPT; ++u) {
    const int t = tid + u * BLK;
    sk_s[t] = (unsigned short)sk[u];
    resp_s[t] = rr[u];
  }
  __syncthreads();

  // build buckets: arrival-ordered slots via packed atomicAdd
#pragma unroll
  for (int u = 0; u < TPT; ++u) {
    const int t = tid + u * BLK;
    const int s_ = sk[u];
    const int sh = (s_ & 1) * 16;
    const int old = atomicAdd(&cnt_s[s_ >> 1], 1 << sh);
    const int slot = (old >> sh) & 0xFFFF;
    if (slot < CAP) buck_s[s_][slot] = (unsigned short)t;
  }
  __syncthreads();

#pragma unroll
  for (int u = 0; u < TPT; ++u) {
    const int t = tid + u * BLK;
    const int s_ = sk[u];
    const int n = (cnt_s[s_ >> 1] >> ((s_ & 1) * 16)) & 0xFFFF;

    float p = k0v[u];                    // prior (answer when rank == 0)

    if (n > 1) {
      if (n <= CAP) {
        // whole bucket in one 8B read
        const uint2 bv = *(const uint2*)&buck_s[s_][0];
        unsigned short e[CAP];
        e[0] = (unsigned short)(bv.x & 0xFFFF);
        e[1] = (unsigned short)(bv.x >> 16);
        e[2] = (unsigned short)(bv.y & 0xFFFF);
        e[3] = (unsigned short)(bv.y >> 16);
        // invalidate: slots beyond n, and touches at/after t
#pragma unroll
        for (int i = 0; i < CAP; ++i)
          if (i >= n || e[i] >= t) e[i] = 0xFFFF;
        // sort4 ascending (invalid 0xFFFF sinks to the end)
#define CSWAP(a_, b_) { const unsigned short x_ = e[a_], y_ = e[b_]; \
                        e[a_] = x_ < y_ ? x_ : y_;                   \
                        e[b_] = x_ < y_ ? y_ : x_; }
        CSWAP(0, 1) CSWAP(2, 3) CSWAP(0, 2) CSWAP(1, 3) CSWAP(1, 2)
#undef CSWAP
        if (e[0] != 0xFFFF) {            // rank > 0: replay in time order
          const float ss = sp[s_];
          const float gg = gp[s_];
          const float tt = tp[s_];
#pragma unroll
          for (int i = 0; i < CAP; ++i)
            if (e[i] != 0xFFFF) p = bkt_update(p, resp_s[e[i]], ss, gg, tt);
        }
      } else {
        // rare overflow (n > CAP): vectorized forward scan, 8 entries / 16B
        const float ss = sp[s_];
        const float gg = gp[s_];
        const float tt = tp[s_];
        const unsigned int tgt2 = (unsigned int)s_ * 0x00010001u; // s_|s_<<16
        const uint4* skv = (const uint4*)sk_s;
        const int nv = (t + 7) >> 3;     // vectors covering [0, t)
        for (int v = 0; v < nv; ++v) {
          const uint4 w = skv[v];        // independent loads -> pipelined
          unsigned int pair[4] = {w.x, w.y, w.z, w.w};
#pragma unroll
          for (int c = 0; c < 4; ++c) {
            const unsigned int ww = pair[c];
            const int j0 = v * 8 + c * 2;
            if ((unsigned short)(ww) == (unsigned short)tgt2 && j0 < t)
              p = bkt_update(p, resp_s[j0], ss, gg, tt);
            if ((unsigned short)(ww >> 16) == (unsigned short)tgt2 && j0 + 1 < t)
              p = bkt_update(p, resp_s[j0 + 1], ss, gg, tt);
          }
        }
      }
    }

    out[base + t] = p;                   // emit pre-update mastery
  }
}

extern "C" void kernel_launch(void* const* d_in, const int* in_sizes, int n_in,
                              void* d_out, int out_size, void* d_ws, size_t ws_size,
                              hipStream_t stream) {
  const int*   skills = (const int*)d_in[0];
  const float* resp   = (const float*)d_in[1];
  const float* k0     = (const float*)d_in[2];
  const float* tp     = (const float*)d_in[3];
  const float* gp     = (const float*)d_in[4];
  const float* sp     = (const float*)d_in[5];
  float* out = (float*)d_out;

  bkt_kernel<<<BKT_B, BLK, 0, stream>>>(skills, resp, k0, tp, gp, sp, out);
}

// Round 10
// 15.190 us; speedup vs baseline: 3.5362x; 2.4195x over previous
//
#include <hip/hip_runtime.h>
#include <limits.h>

// BKT: B=4096 students, T=512 timesteps, K=2048 skills.
// R10: R6's proven structure (linked lists, rank-0 fast path, 256 thr, two
// barriers) with LDS shrunk 12.3KB -> 6KB to probe/exploit block residency:
//  - packed node int per timestep: [21:11]=skill, [10]=resp bit, [9:0]=prev
//    ptr (0x3FF end). resp_s array eliminated; one ds_read_b32 per hop gives
//    ptr+resp+skill.
//  - head table hashed to 1024 entries (4KB); false merges filtered by the
//    node's skill field (~+0.5 alien hops per chain, VALU-cheap).
//  - rank walk also tracks the min matching j + its node -> first replay
//    step needs no rescan (rank==1 is ~83% of replaying lanes).
// R8/R9 bucket family (23.5KB LDS) was 2.4x slower than R6 despite less
// dependent work per lane -> LDS footprint is the prime suspect.

#define BKT_B 4096
#define BKT_T 512
#define BKT_K 2048
#define BLK   256
#define TPT   (BKT_T / BLK)   // 2 timesteps per thread
#define HASH  1024
#define PTR_END 0x3FF

__device__ __forceinline__ float bkt_update(float p, int rbit, float ss,
                                            float gg, float tt) {
  float num, den;
  if (rbit) {                // correct response
    num = p * (1.0f - ss);
    den = num + (1.0f - p) * gg;
  } else {                   // incorrect response
    num = p * ss;
    den = num + (1.0f - p) * (1.0f - gg);
  }
  const float q = num / den; // Bayesian posterior
  return q + (1.0f - q) * tt;// learning transition
}

__global__ __launch_bounds__(BLK) void bkt_kernel(
    const int* __restrict__ skills,
    const float* __restrict__ resp,
    const float* __restrict__ k0,
    const float* __restrict__ tp,
    const float* __restrict__ gp,
    const float* __restrict__ sp,
    float* __restrict__ out) {
  __shared__ int head_s[HASH];   // 4KB: last-arrival t per hash bucket, -1 empty
  __shared__ int node_s[BKT_T];  // 2KB: packed {sk, resp, prev}

  const int b = blockIdx.x;
  const int base = b * BKT_T;
  const int tid = threadIdx.x;

  // coalesced row loads; k0 gather issued early so latency hides under build
  int   sk[TPT];
  float rr[TPT];
  float k0v[TPT];
#pragma unroll
  for (int u = 0; u < TPT; ++u) {
    const int t = tid + u * BLK;
    sk[u] = skills[base + t];
    rr[u] = resp[base + t];
  }
#pragma unroll
  for (int u = 0; u < TPT; ++u)
    k0v[u] = k0[sk[u]];

  // head init: 1024 ints = one int4 store per thread
  ((int4*)head_s)[tid] = make_int4(-1, -1, -1, -1);
  __syncthreads();

  // build hashed linked lists (arrival order arbitrary)
#pragma unroll
  for (int u = 0; u < TPT; ++u) {
    const int t = tid + u * BLK;
    const int s_ = sk[u];
    const int old = atomicExch(&head_s[s_ & (HASH - 1)], t);
    const int ptr = (old < 0) ? PTR_END : old;
    const int rbit = rr[u] > 0.5f ? 1 : 0;
    node_s[t] = ptr | (rbit << 10) | (s_ << 11);
  }
  __syncthreads();

#pragma unroll
  for (int u = 0; u < TPT; ++u) {
    const int t = tid + u * BLK;
    const int s_ = sk[u];
    const int head = head_s[s_ & (HASH - 1)];

    // rank walk; also capture min matching j (first replay target) + node
    int rank = 0, minj = INT_MAX, minnode = 0;
    for (int j = head; j >= 0; ) {
      const int node = node_s[j];
      if (j < t && (node >> 11) == s_) {
        ++rank;
        if (j < minj) { minj = j; minnode = node; }
      }
      const int nx = node & PTR_END;
      j = (nx == PTR_END) ? -1 : nx;
    }

    float p = k0v[u];                  // first-touch prior (rank-0 answer)

    if (rank > 0) {                    // ~12% of lanes: replay in time order
      const float ss = sp[s_];
      const float gg = gp[s_];
      const float tt = tp[s_];
      p = bkt_update(p, (minnode >> 10) & 1, ss, gg, tt);
      int cur = minj;
      for (int rd = 1; rd < rank; ++rd) {
        int best = INT_MAX, bestnode = 0;
        for (int j = head; j >= 0; ) {
          const int node = node_s[j];
          if (j < t && j > cur && (node >> 11) == s_ && j < best) {
            best = j; bestnode = node;
          }
          const int nx = node & PTR_END;
          j = (nx == PTR_END) ? -1 : nx;
        }
        p = bkt_update(p, (bestnode >> 10) & 1, ss, gg, tt);
        cur = best;
      }
    }

    out[base + t] = p;                 // emit pre-update mastery
  }
}

extern "C" void kernel_launch(void* const* d_in, const int* in_sizes, int n_in,
                              void* d_out, int out_size, void* d_ws, size_t ws_size,
                              hipStream_t stream) {
  const int*   skills = (const int*)d_in[0];
  const float* resp   = (const float*)d_in[1];
  const float* k0     = (const float*)d_in[2];
  const float* tp     = (const float*)d_in[3];
  const float* gp     = (const float*)d_in[4];
  const float* sp     = (const float*)d_in[5];
  float* out = (float*)d_out;

  bkt_kernel<<<BKT_B, BLK, 0, stream>>>(skills, resp, k0, tp, gp, sp, out);
}